// Round 1
// baseline (396.027 us; speedup 1.0000x reference)
//
#include <hip/hip_runtime.h>
#include <hip/hip_bf16.h>

// Problem constants (fixed by setup_inputs)
#define Bsz 64
#define Pp  256
#define Dv  1024
#define Dt  768
#define Ss  512
#define Mm  (Bsz*Pp)        // 16384 GEMM rows
#define NSEG 32
#define PPT  8
#define TEMP_INV (1.0f/0.07f)

typedef __attribute__((ext_vector_type(8))) short short8;
typedef __attribute__((ext_vector_type(4))) float floatx4;

__device__ __forceinline__ unsigned short f2bf(float f) {
    unsigned u = __builtin_bit_cast(unsigned, f);
    u += 0x7fffu + ((u >> 16) & 1u);   // round-to-nearest-even
    return (unsigned short)(u >> 16);
}

// K0: W_proj [Dv][Dt] fp32 -> Wt bf16 [Dt][Dv] (transposed, k contiguous)
__global__ __launch_bounds__(256) void k_wt(const float* __restrict__ W,
                                            unsigned short* __restrict__ Wt) {
    __shared__ float tile[32][33];
    int k0 = blockIdx.x * 32, n0 = blockIdx.y * 32;
    int tx = threadIdx.x, ty = threadIdx.y;
    #pragma unroll
    for (int i = 0; i < 32; i += 8)
        tile[ty + i][tx] = W[(size_t)(k0 + ty + i) * Dt + n0 + tx];
    __syncthreads();
    #pragma unroll
    for (int i = 0; i < 32; i += 8)
        Wt[(size_t)(n0 + ty + i) * Dv + k0 + tx] = f2bf(tile[tx][ty + i]);
}

// K1: LayerNorm (biased var) -> bf16 A [Mm][Dv]
__global__ __launch_bounds__(256) void k_ln(const float* __restrict__ x,
                                            const float* __restrict__ gamma,
                                            const float* __restrict__ beta,
                                            unsigned short* __restrict__ out) {
    int row = blockIdx.x;
    int t = threadIdx.x;
    float4 v = ((const float4*)(x + (size_t)row * Dv))[t];
    float s  = v.x + v.y + v.z + v.w;
    float sq = v.x*v.x + v.y*v.y + v.z*v.z + v.w*v.w;
    #pragma unroll
    for (int o = 32; o; o >>= 1) { s += __shfl_down(s, o, 64); sq += __shfl_down(sq, o, 64); }
    __shared__ float ls[4], lq[4];
    int wv = t >> 6, ln = t & 63;
    if (ln == 0) { ls[wv] = s; lq[wv] = sq; }
    __syncthreads();
    if (t == 0) {
        float S = ls[0] + ls[1] + ls[2] + ls[3];
        float Q = lq[0] + lq[1] + lq[2] + lq[3];
        float mean = S * (1.0f / Dv);
        float var  = Q * (1.0f / Dv) - mean * mean;
        ls[0] = mean; lq[0] = rsqrtf(var + 1e-5f);
    }
    __syncthreads();
    float mean = ls[0], rs = lq[0];
    float4 g = ((const float4*)gamma)[t];
    float4 b = ((const float4*)beta)[t];
    ushort4 o;
    o.x = f2bf((v.x - mean) * rs * g.x + b.x);
    o.y = f2bf((v.y - mean) * rs * g.y + b.y);
    o.z = f2bf((v.z - mean) * rs * g.z + b.z);
    o.w = f2bf((v.w - mean) * rs * g.w + b.w);
    ((ushort4*)(out + (size_t)row * Dv))[t] = o;
}

// K2: GEMM  C[16384][768] = A_bf16[16384][1024] @ W[1024][768] + bias
// 64x64 tile per block, BK=32, 4 waves (each wave: 16 rows x 64 cols)
__global__ __launch_bounds__(256) void k_gemm(const unsigned short* __restrict__ A,
                                              const unsigned short* __restrict__ Wt, // [Dt][Dv]
                                              const float* __restrict__ bias,
                                              float* __restrict__ C) {
    __shared__ unsigned short As[64][40];  // [m][k], stride 40 bf16 = 80B (16B aligned)
    __shared__ unsigned short Bs[64][40];  // [n][k]
    int m0 = blockIdx.y * 64;
    int n0 = blockIdx.x * 64;
    int tid = threadIdx.x;
    int wv = tid >> 6, lane = tid & 63;
    int lrow = lane & 15, lk = (lane >> 4) * 8;
    int sm = tid >> 2;            // 0..63
    int sk = (tid & 3) * 8;       // 0,8,16,24
    floatx4 acc[4] = {};
    for (int k0 = 0; k0 < Dv; k0 += 32) {
        uint4 av = *(const uint4*)(A  + (size_t)(m0 + sm) * Dv + k0 + sk);
        uint4 bv = *(const uint4*)(Wt + (size_t)(n0 + sm) * Dv + k0 + sk);
        *(uint4*)&As[sm][sk] = av;
        *(uint4*)&Bs[sm][sk] = bv;
        __syncthreads();
        short8 af = *(const short8*)&As[16 * wv + lrow][lk];
        #pragma unroll
        for (int ts = 0; ts < 4; ++ts) {
            short8 bf = *(const short8*)&Bs[16 * ts + lrow][lk];
            acc[ts] = __builtin_amdgcn_mfma_f32_16x16x32_bf16(af, bf, acc[ts], 0, 0, 0);
        }
        __syncthreads();
    }
    #pragma unroll
    for (int ts = 0; ts < 4; ++ts) {
        #pragma unroll
        for (int r = 0; r < 4; ++r) {
            int m = m0 + 16 * wv + (lane >> 4) * 4 + r;
            int n = n0 + 16 * ts + lrow;
            C[(size_t)m * Dt + n] = acc[ts][r] + bias[n];
        }
    }
}

// K3: segment means [B][NSEG][Dt] = mean of 8 consecutive patches of vis_proj
__global__ __launch_bounds__(256) void k_seg(const float* __restrict__ V,
                                             float* __restrict__ S) {
    int bg = blockIdx.x;                 // b*32+g
    int b = bg >> 5, g = bg & 31;
    const float* base = V + ((size_t)b * Pp + g * PPT) * Dt;
    #pragma unroll
    for (int j = 0; j < 3; ++j) {
        int d = threadIdx.x + 256 * j;
        float s = 0.f;
        #pragma unroll
        for (int p = 0; p < PPT; ++p) s += base[(size_t)p * Dt + d];
        S[(size_t)bg * Dt + d] = s * (1.0f / PPT);
    }
}

// K4: per-row placeholder ranks. code = valid ? rank : -1
__global__ __launch_bounds__(512) void k_rank(const int* __restrict__ ids,
                                              const int* __restrict__ php,
                                              int* __restrict__ code) {
    __shared__ int arr[Ss];
    int b = blockIdx.x, s = threadIdx.x;
    int ph = *php;
    int id = ids[b * Ss + s];
    int m = (id == ph) ? 1 : 0;
    arr[s] = m;
    __syncthreads();
    for (int off = 1; off < Ss; off <<= 1) {
        int v = (s >= off) ? arr[s - off] : 0;
        __syncthreads();
        arr[s] += v;
        __syncthreads();
    }
    int rank = arr[s] - 1;
    code[b * Ss + s] = (m && rank < NSEG) ? rank : -1;
}

// K5: pooled mean over patches, L2-normalize -> nrm [B][Dt]
__global__ __launch_bounds__(256) void k_pool(const float* __restrict__ V,
                                              float* __restrict__ nrm) {
    int b = blockIdx.x, t = threadIdx.x;
    const float* base = V + (size_t)b * Pp * Dt;
    float p0 = 0.f, p1 = 0.f, p2 = 0.f;
    for (int p = 0; p < Pp; ++p) {
        const float* r = base + (size_t)p * Dt;
        p0 += r[t]; p1 += r[t + 256]; p2 += r[t + 512];
    }
    p0 *= (1.0f / Pp); p1 *= (1.0f / Pp); p2 *= (1.0f / Pp);
    float sq = p0*p0 + p1*p1 + p2*p2;
    #pragma unroll
    for (int o = 32; o; o >>= 1) sq += __shfl_down(sq, o, 64);
    __shared__ float ls[4];
    int wv = t >> 6, ln = t & 63;
    if (ln == 0) ls[wv] = sq;
    __syncthreads();
    if (t == 0) ls[0] = ls[0] + ls[1] + ls[2] + ls[3];
    __syncthreads();
    float inv = 1.0f / sqrtf(ls[0]);
    nrm[(size_t)b * Dt + t]       = p0 * inv;
    nrm[(size_t)b * Dt + t + 256] = p1 * inv;
    nrm[(size_t)b * Dt + t + 512] = p2 * inv;
}

// K6: assemble text_emb: seg_means row if valid placeholder else wte[id]
__global__ __launch_bounds__(192) void k_emb(const int* __restrict__ ids,
                                             const int* __restrict__ code,
                                             const float* __restrict__ seg,
                                             const float* __restrict__ wte,
                                             float* __restrict__ out) {
    int bs = blockIdx.x;
    int b = bs >> 9;
    int c = code[bs];
    const float4* src = (c >= 0)
        ? (const float4*)(seg + ((size_t)(b * NSEG + c)) * Dt)
        : (const float4*)(wte + (size_t)ids[bs] * Dt);
    ((float4*)(out + (size_t)bs * Dt))[threadIdx.x] = src[threadIdx.x];
}

// K7a: sim[i][j] = (nrm_i . nrm_j) / TEMP, one block per row i
__global__ __launch_bounds__(256) void k_sim(const float* __restrict__ nrm,
                                             float* __restrict__ simg) {
    __shared__ float ls[Dt];
    int i = blockIdx.x, t = threadIdx.x;
    ls[t]       = nrm[(size_t)i * Dt + t];
    ls[t + 256] = nrm[(size_t)i * Dt + t + 256];
    ls[t + 512] = nrm[(size_t)i * Dt + t + 512];
    __syncthreads();
    int jj = t >> 2, q = t & 3;
    const float* nj = nrm + (size_t)jj * Dt + q * 192;
    const float* li = ls + q * 192;
    float s = 0.f;
    for (int d = 0; d < 192; ++d) s += li[d] * nj[d];
    s += __shfl_down(s, 2, 4);
    s += __shfl_down(s, 1, 4);
    if (q == 0) simg[i * 64 + jj] = s * TEMP_INV;
}

// K7b: symmetric CE loss from sim
__global__ __launch_bounds__(64) void k_loss(const float* __restrict__ simg,
                                             float* __restrict__ lossp) {
    __shared__ float sim[64][65];
    int t = threadIdx.x;
    for (int i = 0; i < 64; ++i) sim[i][t] = simg[i * 64 + t];
    __syncthreads();
    float mr = -1e30f, mc = -1e30f;
    for (int j = 0; j < 64; ++j) {
        mr = fmaxf(mr, sim[t][j]);
        mc = fmaxf(mc, sim[j][t]);
    }
    float sr = 0.f, sc = 0.f;
    for (int j = 0; j < 64; ++j) {
        sr += expf(sim[t][j] - mr);
        sc += expf(sim[j][t] - mc);
    }
    float lser = mr + logf(sr);
    float lsec = mc + logf(sc);
    float p = (lser - sim[t][t]) + (lsec - sim[t][t]);
    #pragma unroll
    for (int o = 32; o; o >>= 1) p += __shfl_down(p, o, 64);
    if (t == 0) *lossp = p * (1.0f / 128.0f);
}

extern "C" void kernel_launch(void* const* d_in, const int* in_sizes, int n_in,
                              void* d_out, int out_size, void* d_ws, size_t ws_size,
                              hipStream_t stream) {
    const float* vis   = (const float*)d_in[0];
    const float* gamma = (const float*)d_in[1];
    const float* beta  = (const float*)d_in[2];
    const float* W     = (const float*)d_in[3];
    const float* bproj = (const float*)d_in[4];
    const float* wte   = (const float*)d_in[5];
    const int*   ids   = (const int*)d_in[6];
    const int*   php   = (const int*)d_in[7];

    char* ws = (char*)d_ws;
    // workspace layout (bytes)
    unsigned short* Abf  = (unsigned short*)(ws + 0);         // 16384*1024*2 = 33554432
    unsigned short* Wt   = (unsigned short*)(ws + 33554432);  // 768*1024*2   = 1572864
    float*          vprj = (float*)(ws + 35127296);           // 16384*768*4  = 50331648
    float*          seg  = (float*)(ws + 85458944);           // 64*32*768*4  = 6291456
    float*          nrm  = (float*)(ws + 91750400);           // 64*768*4     = 196608
    int*            code = (int*)(ws + 91947008);             // 64*512*4     = 131072
    float*          simg = (float*)(ws + 92078080);           // 64*64*4      = 16384

    float* out = (float*)d_out;

    k_wt  <<<dim3(Dv/32, Dt/32), dim3(32, 8), 0, stream>>>(W, Wt);
    k_ln  <<<Mm, 256, 0, stream>>>(vis, gamma, beta, Abf);
    k_gemm<<<dim3(Dt/64, Mm/64), 256, 0, stream>>>(Abf, Wt, bproj, vprj);
    k_seg <<<Bsz*NSEG, 256, 0, stream>>>(vprj, seg);
    k_rank<<<Bsz, Ss, 0, stream>>>(ids, php, code);
    k_pool<<<Bsz, 256, 0, stream>>>(vprj, nrm);
    k_emb <<<Bsz*Ss, 192, 0, stream>>>(ids, code, seg, wte, out);
    k_sim <<<64, 256, 0, stream>>>(nrm, simg);
    k_loss<<<1, 64, 0, stream>>>(simg, out + (size_t)Bsz * Ss * Dt);
}

// Round 2
// 326.827 us; speedup vs baseline: 1.2117x; 1.2117x over previous
//
#include <hip/hip_runtime.h>
#include <hip/hip_bf16.h>

// Problem constants (fixed by setup_inputs)
#define Bsz 64
#define Pp  256
#define Dv  1024
#define Dt  768
#define Ss  512
#define NSEG 32
#define PPT  8
#define MSEG (Bsz*NSEG)     // 2048 GEMM rows (segment-summed)
#define TEMP_INV (1.0f/0.07f)

typedef __attribute__((ext_vector_type(8))) short short8;
typedef __attribute__((ext_vector_type(4))) float floatx4;

__device__ __forceinline__ unsigned short f2bf(float f) {
    unsigned u = __builtin_bit_cast(unsigned, f);
    u += 0x7fffu + ((u >> 16) & 1u);   // round-to-nearest-even
    return (unsigned short)(u >> 16);
}

// K0: W_proj [Dv][Dt] fp32 -> Wt bf16 [Dt][Dv] (transposed, k contiguous)
__global__ __launch_bounds__(256) void k_wt(const float* __restrict__ W,
                                            unsigned short* __restrict__ Wt) {
    __shared__ float tile[32][33];
    int k0 = blockIdx.x * 32, n0 = blockIdx.y * 32;
    int tx = threadIdx.x, ty = threadIdx.y;
    #pragma unroll
    for (int i = 0; i < 32; i += 8)
        tile[ty + i][tx] = W[(size_t)(k0 + ty + i) * Dt + n0 + tx];
    __syncthreads();
    #pragma unroll
    for (int i = 0; i < 32; i += 8)
        Wt[(size_t)(n0 + ty + i) * Dv + k0 + tx] = f2bf(tile[tx][ty + i]);
}

// K1: fused LayerNorm + 8-row segment sum -> sA bf16 [MSEG][Dv]
// one block per segment; 8 waves, one row (patch) each
__global__ __launch_bounds__(512) void k_ln_seg(const float* __restrict__ x,
                                                const float* __restrict__ gamma,
                                                const float* __restrict__ beta,
                                                unsigned short* __restrict__ sA) {
    __shared__ float sg[8][Dv];
    int seg = blockIdx.x;            // 0..MSEG-1
    int t = threadIdx.x;
    int w = t >> 6, l = t & 63;
    const float* row = x + ((size_t)seg * PPT + w) * Dv;
    float4 v[4];
    float s = 0.f, sq = 0.f;
    #pragma unroll
    for (int j = 0; j < 4; ++j) {
        v[j] = ((const float4*)row)[l + 64 * j];
        s  += v[j].x + v[j].y + v[j].z + v[j].w;
        sq += v[j].x*v[j].x + v[j].y*v[j].y + v[j].z*v[j].z + v[j].w*v[j].w;
    }
    #pragma unroll
    for (int o = 32; o; o >>= 1) { s += __shfl_down(s, o, 64); sq += __shfl_down(sq, o, 64); }
    s  = __shfl(s, 0, 64);
    sq = __shfl(sq, 0, 64);
    float mean = s * (1.0f / Dv);
    float rs = rsqrtf(sq * (1.0f / Dv) - mean * mean + 1e-5f);
    #pragma unroll
    for (int j = 0; j < 4; ++j) {
        int c4 = l + 64 * j;
        float4 g = ((const float4*)gamma)[c4];
        float4 b = ((const float4*)beta)[c4];
        float4 o;
        o.x = (v[j].x - mean) * rs * g.x + b.x;
        o.y = (v[j].y - mean) * rs * g.y + b.y;
        o.z = (v[j].z - mean) * rs * g.z + b.z;
        o.w = (v[j].w - mean) * rs * g.w + b.w;
        *(float4*)&sg[w][c4 * 4] = o;
    }
    __syncthreads();
    // phase 2: sum the 8 rows per column, round to bf16
    #pragma unroll
    for (int cc = 0; cc < 2; ++cc) {
        int c = t + cc * 512;
        float acc = 0.f;
        #pragma unroll
        for (int r = 0; r < 8; ++r) acc += sg[r][c];
        sA[(size_t)seg * Dv + c] = f2bf(acc);
    }
}

// K2: GEMM  seg[2048][768] = sA_bf16[2048][1024] @ W[1024][768]; epilogue /8 + bias
// 64x64 tile per block, BK=32, 4 waves (each wave: 16 rows x 64 cols)
__global__ __launch_bounds__(256) void k_gemm(const unsigned short* __restrict__ A,
                                              const unsigned short* __restrict__ Wt, // [Dt][Dv]
                                              const float* __restrict__ bias,
                                              float* __restrict__ C) {
    __shared__ unsigned short As[64][40];  // [m][k], stride 40 bf16 = 80B
    __shared__ unsigned short Bs[64][40];  // [n][k]
    int m0 = blockIdx.y * 64;
    int n0 = blockIdx.x * 64;
    int tid = threadIdx.x;
    int wv = tid >> 6, lane = tid & 63;
    int lrow = lane & 15, lk = (lane >> 4) * 8;
    int sm = tid >> 2;            // 0..63
    int sk = (tid & 3) * 8;       // 0,8,16,24
    floatx4 acc[4] = {};
    for (int k0 = 0; k0 < Dv; k0 += 32) {
        uint4 av = *(const uint4*)(A  + (size_t)(m0 + sm) * Dv + k0 + sk);
        uint4 bv = *(const uint4*)(Wt + (size_t)(n0 + sm) * Dv + k0 + sk);
        *(uint4*)&As[sm][sk] = av;
        *(uint4*)&Bs[sm][sk] = bv;
        __syncthreads();
        short8 af = *(const short8*)&As[16 * wv + lrow][lk];
        #pragma unroll
        for (int ts = 0; ts < 4; ++ts) {
            short8 bf = *(const short8*)&Bs[16 * ts + lrow][lk];
            acc[ts] = __builtin_amdgcn_mfma_f32_16x16x32_bf16(af, bf, acc[ts], 0, 0, 0);
        }
        __syncthreads();
    }
    #pragma unroll
    for (int ts = 0; ts < 4; ++ts) {
        #pragma unroll
        for (int r = 0; r < 4; ++r) {
            int m = m0 + 16 * wv + (lane >> 4) * 4 + r;
            int n = n0 + 16 * ts + lrow;
            C[(size_t)m * Dt + n] = acc[ts][r] * 0.125f + bias[n];
        }
    }
}

// K4: per-row placeholder ranks. code = valid ? rank : -1
__global__ __launch_bounds__(512) void k_rank(const int* __restrict__ ids,
                                              const int* __restrict__ php,
                                              int* __restrict__ code) {
    __shared__ int arr[Ss];
    int b = blockIdx.x, s = threadIdx.x;
    int ph = *php;
    int id = ids[b * Ss + s];
    int m = (id == ph) ? 1 : 0;
    arr[s] = m;
    __syncthreads();
    for (int off = 1; off < Ss; off <<= 1) {
        int v = (s >= off) ? arr[s - off] : 0;
        __syncthreads();
        arr[s] += v;
        __syncthreads();
    }
    int rank = arr[s] - 1;
    code[b * Ss + s] = (m && rank < NSEG) ? rank : -1;
}

// K5: pooled = mean over 32 seg_means (== mean over patches), L2-normalize
__global__ __launch_bounds__(256) void k_pool(const float* __restrict__ seg,
                                              float* __restrict__ nrm) {
    int b = blockIdx.x, t = threadIdx.x;
    const float* base = seg + (size_t)b * NSEG * Dt;
    float p0 = 0.f, p1 = 0.f, p2 = 0.f;
    for (int g = 0; g < NSEG; ++g) {
        const float* r = base + (size_t)g * Dt;
        p0 += r[t]; p1 += r[t + 256]; p2 += r[t + 512];
    }
    p0 *= (1.0f / NSEG); p1 *= (1.0f / NSEG); p2 *= (1.0f / NSEG);
    float sq = p0*p0 + p1*p1 + p2*p2;
    #pragma unroll
    for (int o = 32; o; o >>= 1) sq += __shfl_down(sq, o, 64);
    __shared__ float ls[4];
    int wv = t >> 6, ln = t & 63;
    if (ln == 0) ls[wv] = sq;
    __syncthreads();
    if (t == 0) ls[0] = ls[0] + ls[1] + ls[2] + ls[3];
    __syncthreads();
    float inv = 1.0f / sqrtf(ls[0]);
    nrm[(size_t)b * Dt + t]       = p0 * inv;
    nrm[(size_t)b * Dt + t + 256] = p1 * inv;
    nrm[(size_t)b * Dt + t + 512] = p2 * inv;
}

// K6: assemble text_emb: seg_means row if valid placeholder else wte[id]
__global__ __launch_bounds__(192) void k_emb(const int* __restrict__ ids,
                                             const int* __restrict__ code,
                                             const float* __restrict__ seg,
                                             const float* __restrict__ wte,
                                             float* __restrict__ out) {
    int bs = blockIdx.x;
    int b = bs >> 9;
    int c = code[bs];
    const float4* src = (c >= 0)
        ? (const float4*)(seg + ((size_t)(b * NSEG + c)) * Dt)
        : (const float4*)(wte + (size_t)ids[bs] * Dt);
    ((float4*)(out + (size_t)bs * Dt))[threadIdx.x] = src[threadIdx.x];
}

// K7a: sim[i][j] = (nrm_i . nrm_j) / TEMP, one block per row i
__global__ __launch_bounds__(256) void k_sim(const float* __restrict__ nrm,
                                             float* __restrict__ simg) {
    __shared__ float ls[Dt];
    int i = blockIdx.x, t = threadIdx.x;
    ls[t]       = nrm[(size_t)i * Dt + t];
    ls[t + 256] = nrm[(size_t)i * Dt + t + 256];
    ls[t + 512] = nrm[(size_t)i * Dt + t + 512];
    __syncthreads();
    int jj = t >> 2, q = t & 3;
    const float* nj = nrm + (size_t)jj * Dt + q * 192;
    const float* li = ls + q * 192;
    float s = 0.f;
    for (int d = 0; d < 192; ++d) s += li[d] * nj[d];
    s += __shfl_down(s, 2, 4);
    s += __shfl_down(s, 1, 4);
    if (q == 0) simg[i * 64 + jj] = s * TEMP_INV;
}

// K7b: symmetric CE loss from sim
__global__ __launch_bounds__(64) void k_loss(const float* __restrict__ simg,
                                             float* __restrict__ lossp) {
    __shared__ float sim[64][65];
    int t = threadIdx.x;
    for (int i = 0; i < 64; ++i) sim[i][t] = simg[i * 64 + t];
    __syncthreads();
    float mr = -1e30f, mc = -1e30f;
    for (int j = 0; j < 64; ++j) {
        mr = fmaxf(mr, sim[t][j]);
        mc = fmaxf(mc, sim[j][t]);
    }
    float sr = 0.f, sc = 0.f;
    for (int j = 0; j < 64; ++j) {
        sr += expf(sim[t][j] - mr);
        sc += expf(sim[j][t] - mc);
    }
    float lser = mr + logf(sr);
    float lsec = mc + logf(sc);
    float p = (lser - sim[t][t]) + (lsec - sim[t][t]);
    #pragma unroll
    for (int o = 32; o; o >>= 1) p += __shfl_down(p, o, 64);
    if (t == 0) *lossp = p * (1.0f / 128.0f);
}

extern "C" void kernel_launch(void* const* d_in, const int* in_sizes, int n_in,
                              void* d_out, int out_size, void* d_ws, size_t ws_size,
                              hipStream_t stream) {
    const float* vis   = (const float*)d_in[0];
    const float* gamma = (const float*)d_in[1];
    const float* beta  = (const float*)d_in[2];
    const float* W     = (const float*)d_in[3];
    const float* bproj = (const float*)d_in[4];
    const float* wte   = (const float*)d_in[5];
    const int*   ids   = (const int*)d_in[6];
    const int*   php   = (const int*)d_in[7];

    char* ws = (char*)d_ws;
    // workspace layout (bytes)
    unsigned short* sA   = (unsigned short*)(ws + 0);        // 2048*1024*2 = 4194304
    unsigned short* Wt   = (unsigned short*)(ws + 4194304);  // 768*1024*2  = 1572864
    float*          seg  = (float*)(ws + 5767168);           // 2048*768*4  = 6291456
    float*          nrm  = (float*)(ws + 12058624);          // 64*768*4    = 196608
    int*            code = (int*)(ws + 12255232);            // 64*512*4    = 131072
    float*          simg = (float*)(ws + 12386304);          // 64*64*4     = 16384

    float* out = (float*)d_out;

    k_wt    <<<dim3(Dv/32, Dt/32), dim3(32, 8), 0, stream>>>(W, Wt);
    k_ln_seg<<<MSEG, 512, 0, stream>>>(vis, gamma, beta, sA);
    k_gemm  <<<dim3(Dt/64, MSEG/64), 256, 0, stream>>>(sA, Wt, bproj, seg);
    k_rank  <<<Bsz, Ss, 0, stream>>>(ids, php, code);
    k_pool  <<<Bsz, 256, 0, stream>>>(seg, nrm);
    k_emb   <<<Bsz*Ss, 192, 0, stream>>>(ids, code, seg, wte, out);
    k_sim   <<<64, 256, 0, stream>>>(nrm, simg);
    k_loss  <<<1, 64, 0, stream>>>(simg, out + (size_t)Bsz * Ss * Dt);
}

// Round 3
// 314.628 us; speedup vs baseline: 1.2587x; 1.0388x over previous
//
#include <hip/hip_runtime.h>
#include <hip/hip_bf16.h>

// Problem constants (fixed by setup_inputs)
#define Bsz 64
#define Pp  256
#define Dv  1024
#define Dt  768
#define Ss  512
#define NSEG 32
#define PPT  8
#define MSEG (Bsz*NSEG)     // 2048 GEMM rows (segment-summed)
#define TEMP_INV (1.0f/0.07f)
#define WT_BLOCKS 768       // (Dv/32)*(Dt/32) = 32*24

typedef __attribute__((ext_vector_type(8))) short short8;
typedef __attribute__((ext_vector_type(4))) float floatx4;

__device__ __forceinline__ unsigned short f2bf(float f) {
    unsigned u = __builtin_bit_cast(unsigned, f);
    u += 0x7fffu + ((u >> 16) & 1u);   // round-to-nearest-even
    return (unsigned short)(u >> 16);
}

// K1: merged prep.
//   blocks [0, WT_BLOCKS):          W [Dv][Dt] fp32 -> Wt bf16 [Dt][Dv] (32x32 tiles)
//   blocks [WT_BLOCKS, +MSEG):      LayerNorm + 8-patch segment sum -> sA bf16 [MSEG][Dv]
__global__ __launch_bounds__(512) void k_prep(const float* __restrict__ W,
                                              unsigned short* __restrict__ Wt,
                                              const float* __restrict__ x,
                                              const float* __restrict__ gamma,
                                              const float* __restrict__ beta,
                                              unsigned short* __restrict__ sA) {
    __shared__ float smem[8 * Dv];   // 32 KB, aliased by both roles
    int t = threadIdx.x;
    if (blockIdx.x < WT_BLOCKS) {
        // ---- W transpose+cast: tile (k0, n0) ----
        float (*tile)[33] = (float (*)[33])smem;
        int idx = blockIdx.x;
        int k0 = (idx & 31) * 32, n0 = (idx >> 5) * 32;
        int tx = t & 31, ty = t >> 5;          // ty 0..15
        #pragma unroll
        for (int i = 0; i < 32; i += 16)
            tile[ty + i][tx] = W[(size_t)(k0 + ty + i) * Dt + n0 + tx];
        __syncthreads();
        #pragma unroll
        for (int i = 0; i < 32; i += 16)
            Wt[(size_t)(n0 + ty + i) * Dv + k0 + tx] = f2bf(tile[tx][ty + i]);
        return;
    }
    // ---- LN + segment-sum ----
    float (*sg)[Dv] = (float (*)[Dv])smem;
    int seg = blockIdx.x - WT_BLOCKS;      // 0..MSEG-1
    int w = t >> 6, l = t & 63;
    const float* row = x + ((size_t)seg * PPT + w) * Dv;
    float4 v[4];
    float s = 0.f, sq = 0.f;
    #pragma unroll
    for (int j = 0; j < 4; ++j) {
        v[j] = ((const float4*)row)[l + 64 * j];
        s  += v[j].x + v[j].y + v[j].z + v[j].w;
        sq += v[j].x*v[j].x + v[j].y*v[j].y + v[j].z*v[j].z + v[j].w*v[j].w;
    }
    #pragma unroll
    for (int o = 32; o; o >>= 1) { s += __shfl_down(s, o, 64); sq += __shfl_down(sq, o, 64); }
    s  = __shfl(s, 0, 64);
    sq = __shfl(sq, 0, 64);
    float mean = s * (1.0f / Dv);
    float rs = rsqrtf(sq * (1.0f / Dv) - mean * mean + 1e-5f);
    #pragma unroll
    for (int j = 0; j < 4; ++j) {
        int c4 = l + 64 * j;
        float4 g = ((const float4*)gamma)[c4];
        float4 b = ((const float4*)beta)[c4];
        float4 o;
        o.x = (v[j].x - mean) * rs * g.x + b.x;
        o.y = (v[j].y - mean) * rs * g.y + b.y;
        o.z = (v[j].z - mean) * rs * g.z + b.z;
        o.w = (v[j].w - mean) * rs * g.w + b.w;
        *(float4*)&sg[w][c4 * 4] = o;
    }
    __syncthreads();
    #pragma unroll
    for (int cc = 0; cc < 2; ++cc) {
        int c = t + cc * 512;
        float acc = 0.f;
        #pragma unroll
        for (int r = 0; r < 8; ++r) acc += sg[r][c];
        sA[(size_t)seg * Dv + c] = f2bf(acc);
    }
}

// K2: GEMM  seg[2048][768] = sA_bf16[2048][1024] @ W[1024][768]; epilogue /8 + bias
// 64x64 tile, BK=64, register-prefetch double buffer, LDS stride 72 (bank-balanced)
__global__ __launch_bounds__(256) void k_gemm(const unsigned short* __restrict__ A,
                                              const unsigned short* __restrict__ Wt, // [Dt][Dv]
                                              const float* __restrict__ bias,
                                              float* __restrict__ C) {
    __shared__ unsigned short As[64][72];
    __shared__ unsigned short Bs[64][72];
    int m0 = blockIdx.y * 64;
    int n0 = blockIdx.x * 64;
    int tid = threadIdx.x;
    int wv = tid >> 6, lane = tid & 63;
    int lrow = lane & 15, lk = (lane >> 4) * 8;
    int sm = tid >> 2;            // 0..63 staging row
    int sk = (tid & 3) * 16;      // 0,16,32,48 (elements)
    const unsigned short* Ap = A  + (size_t)(m0 + sm) * Dv + sk;
    const unsigned short* Bp = Wt + (size_t)(n0 + sm) * Dv + sk;
    uint4 a0 = *(const uint4*)Ap, a1 = *(const uint4*)(Ap + 8);
    uint4 b0 = *(const uint4*)Bp, b1 = *(const uint4*)(Bp + 8);
    floatx4 acc[4] = {};
    for (int k0 = 0; k0 < Dv; k0 += 64) {
        *(uint4*)&As[sm][sk]     = a0;
        *(uint4*)&As[sm][sk + 8] = a1;
        *(uint4*)&Bs[sm][sk]     = b0;
        *(uint4*)&Bs[sm][sk + 8] = b1;
        __syncthreads();
        if (k0 + 64 < Dv) {
            Ap += 64; Bp += 64;
            a0 = *(const uint4*)Ap; a1 = *(const uint4*)(Ap + 8);
            b0 = *(const uint4*)Bp; b1 = *(const uint4*)(Bp + 8);
        }
        #pragma unroll
        for (int ks = 0; ks < 2; ++ks) {
            short8 af = *(const short8*)&As[16 * wv + lrow][ks * 32 + lk];
            #pragma unroll
            for (int ts = 0; ts < 4; ++ts) {
                short8 bf = *(const short8*)&Bs[16 * ts + lrow][ks * 32 + lk];
                acc[ts] = __builtin_amdgcn_mfma_f32_16x16x32_bf16(af, bf, acc[ts], 0, 0, 0);
            }
        }
        __syncthreads();
    }
    #pragma unroll
    for (int ts = 0; ts < 4; ++ts) {
        #pragma unroll
        for (int r = 0; r < 4; ++r) {
            int m = m0 + 16 * wv + (lane >> 4) * 4 + r;
            int n = n0 + 16 * ts + lrow;
            C[(size_t)m * Dt + n] = acc[ts][r] * 0.125f + bias[n];
        }
    }
}

// K3: merged rank + pool.
//   blocks [0,64):    per-row placeholder rank scan -> code
//   blocks [64,128):  pooled = mean over 32 seg rows, L2-normalize -> nrm
//   block 0 thread 0 also zero-inits the loss accumulator (consumed by k_rowlse).
__global__ __launch_bounds__(512) void k_rankpool(const int* __restrict__ ids,
                                                  const int* __restrict__ php,
                                                  int* __restrict__ code,
                                                  const float* __restrict__ seg,
                                                  float* __restrict__ nrm,
                                                  float* __restrict__ lossp) {
    __shared__ int arr[Ss];
    __shared__ float red[8];
    int t = threadIdx.x;
    if (blockIdx.x < 64) {
        int b = blockIdx.x;
        if (b == 0 && t == 0) *lossp = 0.f;
        int ph = *php;
        int id = ids[b * Ss + t];
        int m = (id == ph) ? 1 : 0;
        arr[t] = m;
        __syncthreads();
        for (int off = 1; off < Ss; off <<= 1) {
            int v = (t >= off) ? arr[t - off] : 0;
            __syncthreads();
            arr[t] += v;
            __syncthreads();
        }
        int rank = arr[t] - 1;
        code[b * Ss + t] = (m && rank < NSEG) ? rank : -1;
        return;
    }
    int b = blockIdx.x - 64;
    const float* base = seg + (size_t)b * NSEG * Dt;
    float p0 = 0.f, p1 = 0.f;
    for (int g = 0; g < NSEG; ++g) p0 += base[(size_t)g * Dt + t];
    if (t < 256)
        for (int g = 0; g < NSEG; ++g) p1 += base[(size_t)g * Dt + 512 + t];
    p0 *= (1.0f / NSEG); p1 *= (1.0f / NSEG);
    float sq = p0 * p0 + (t < 256 ? p1 * p1 : 0.f);
    #pragma unroll
    for (int o = 32; o; o >>= 1) sq += __shfl_down(sq, o, 64);
    int wv = t >> 6, ln = t & 63;
    if (ln == 0) red[wv] = sq;
    __syncthreads();
    if (t == 0) {
        float S = 0.f;
        #pragma unroll
        for (int i = 0; i < 8; ++i) S += red[i];
        red[0] = 1.0f / sqrtf(S);
    }
    __syncthreads();
    float inv = red[0];
    nrm[(size_t)b * Dt + t] = p0 * inv;
    if (t < 256) nrm[(size_t)b * Dt + 512 + t] = p1 * inv;
}

// K4: assemble text_emb: seg_means row if valid placeholder else wte[id]
__global__ __launch_bounds__(192) void k_emb(const int* __restrict__ ids,
                                             const int* __restrict__ code,
                                             const float* __restrict__ seg,
                                             const float* __restrict__ wte,
                                             float* __restrict__ out) {
    int bs = blockIdx.x;
    int b = bs >> 9;
    int c = code[bs];
    const float4* src = (c >= 0)
        ? (const float4*)(seg + ((size_t)(b * NSEG + c)) * Dt)
        : (const float4*)(wte + (size_t)ids[bs] * Dt);
    ((float4*)(out + (size_t)bs * Dt))[threadIdx.x] = src[threadIdx.x];
}

// K5: row i of sim (symmetric!), logsumexp, atomic-accumulate loss.
// loss = mean_i(lse_i - sim_ii)  ==  (ce_row + ce_col)/2 since sim = nrm@nrm.T is symmetric.
__global__ __launch_bounds__(256) void k_rowlse(const float* __restrict__ nrm,
                                                float* __restrict__ lossp) {
    __shared__ float ls[Dt];
    __shared__ float simrow[64];
    int i = blockIdx.x, t = threadIdx.x;
    ls[t]       = nrm[(size_t)i * Dt + t];
    ls[t + 256] = nrm[(size_t)i * Dt + t + 256];
    ls[t + 512] = nrm[(size_t)i * Dt + t + 512];
    __syncthreads();
    int jj = t >> 2, q = t & 3;
    const float* nj = nrm + (size_t)jj * Dt + q * 192;
    const float* li = ls + q * 192;
    float s = 0.f;
    for (int d = 0; d < 192; ++d) s += li[d] * nj[d];
    s += __shfl_down(s, 2, 4);
    s += __shfl_down(s, 1, 4);
    if (q == 0) simrow[jj] = s * TEMP_INV;
    __syncthreads();
    if (t < 64) {
        // |sim| <= 14.3 -> exp <= 1.6e6, no max-shift needed in fp32
        float sum = expf(simrow[t]);
        #pragma unroll
        for (int o = 32; o; o >>= 1) sum += __shfl_down(sum, o, 64);
        if (t == 0)
            atomicAdd(lossp, (logf(sum) - simrow[i]) * (1.0f / 64.0f));
    }
}

extern "C" void kernel_launch(void* const* d_in, const int* in_sizes, int n_in,
                              void* d_out, int out_size, void* d_ws, size_t ws_size,
                              hipStream_t stream) {
    const float* vis   = (const float*)d_in[0];
    const float* gamma = (const float*)d_in[1];
    const float* beta  = (const float*)d_in[2];
    const float* W     = (const float*)d_in[3];
    const float* bproj = (const float*)d_in[4];
    const float* wte   = (const float*)d_in[5];
    const int*   ids   = (const int*)d_in[6];
    const int*   php   = (const int*)d_in[7];

    char* ws = (char*)d_ws;
    unsigned short* sA   = (unsigned short*)(ws + 0);        // 2048*1024*2 = 4194304
    unsigned short* Wt   = (unsigned short*)(ws + 4194304);  // 768*1024*2  = 1572864
    float*          seg  = (float*)(ws + 5767168);           // 2048*768*4  = 6291456
    float*          nrm  = (float*)(ws + 12058624);          // 64*768*4    = 196608
    int*            code = (int*)(ws + 12255232);            // 64*512*4    = 131072

    float* out = (float*)d_out;
    float* lossp = out + (size_t)Bsz * Ss * Dt;

    k_prep    <<<WT_BLOCKS + MSEG, 512, 0, stream>>>(W, Wt, vis, gamma, beta, sA);
    k_gemm    <<<dim3(Dt/64, MSEG/64), 256, 0, stream>>>(sA, Wt, bproj, seg);
    k_rankpool<<<128, 512, 0, stream>>>(ids, php, code, seg, nrm, lossp);
    k_emb     <<<Bsz*Ss, 192, 0, stream>>>(ids, code, seg, wte, out);
    k_rowlse  <<<64, 256, 0, stream>>>(nrm, lossp);
}